// Round 7
// baseline (415.257 us; speedup 1.0000x reference)
//
#include <hip/hip_runtime.h>
#include <hip/hip_bf16.h>

#define NODELEN 394
#define IN_DIM 788
#define H2DIM 192
#define EMBDIM 128
#define NCHUNK 197   // 394 elems = 197 x (float2 | uint-packed-bf16x2)

typedef __attribute__((ext_vector_type(4))) float f32x4;
typedef __attribute__((ext_vector_type(8))) short bfrag;  // 8 bf16 = 4 VGPRs

static __device__ __forceinline__ unsigned short f2bf(float f) {
    union { float f; unsigned u; } v; v.f = f;
    unsigned r = v.u + 0x7FFFu + ((v.u >> 16) & 1u);  // round-to-nearest-even
    return (unsigned short)(r >> 16);
}
static __device__ __forceinline__ float bf2f(unsigned short h) {
    union { unsigned u; float f; } v; v.u = ((unsigned)h) << 16;
    return v.f;
}

// ---------------- CSR build ----------------

__global__ void count_deg(const int* __restrict__ dst, int* __restrict__ deg, int e) {
    int i = blockIdx.x * blockDim.x + threadIdx.x;
    if (i < e) atomicAdd(&deg[dst[i]], 1);
}

__global__ void block_sum(const int* __restrict__ deg, int* __restrict__ bsum, int n) {
    __shared__ int s[256];
    int t = threadIdx.x;
    int i = blockIdx.x * 256 + t;
    s[t] = (i < n) ? deg[i] : 0;
    __syncthreads();
    for (int d = 128; d > 0; d >>= 1) {
        if (t < d) s[t] += s[t + d];
        __syncthreads();
    }
    if (t == 0) bsum[blockIdx.x] = s[0];
}

__global__ void scan_bsums(int* bsum, int nb) {
    __shared__ int s[256];
    int t = threadIdx.x;
    int x0 = (t < nb) ? bsum[t] : 0;
    s[t] = x0;
    __syncthreads();
    for (int d = 1; d < 256; d <<= 1) {
        int u = (t >= d) ? s[t - d] : 0;
        __syncthreads();
        s[t] += u;
        __syncthreads();
    }
    if (t < nb) bsum[t] = s[t] - x0;
}

// also emits inv = 1/max(deg,1)
__global__ void block_scan(const int* __restrict__ deg, const int* __restrict__ boff,
                           int* __restrict__ rowstart, int* __restrict__ cursor,
                           float* __restrict__ inv, int n) {
    __shared__ int s[256];
    int t = threadIdx.x;
    int i = blockIdx.x * 256 + t;
    int x0 = (i < n) ? deg[i] : 0;
    s[t] = x0;
    __syncthreads();
    for (int d = 1; d < 256; d <<= 1) {
        int u = (t >= d) ? s[t - d] : 0;
        __syncthreads();
        s[t] += u;
        __syncthreads();
    }
    if (i < n) {
        int r = boff[blockIdx.x] + s[t] - x0;
        rowstart[i] = r;
        cursor[i] = r;
        inv[i] = 1.0f / fmaxf((float)x0, 1.0f);
    }
}

__global__ void fill_edges(const int* __restrict__ src, const int* __restrict__ dst,
                           int* __restrict__ cursor, int* __restrict__ elist, int e) {
    int i = blockIdx.x * blockDim.x + threadIdx.x;
    if (i < e) {
        int p = atomicAdd(&cursor[dst[i]], 1);
        elist[p] = src[i];
    }
}

// ---------------- aggregation (gather, float2-vectorized, 4-deep neighbor ILP) ----

__global__ __launch_bounds__(256) void gather1(
        const float* __restrict__ feat, const int* __restrict__ rowstart,
        const int* __restrict__ deg, const float* __restrict__ inv,
        const int* __restrict__ elist, unsigned short* __restrict__ h1) {
    const int node = blockIdx.x;
    const int c = threadIdx.x;          // float2 chunk id, 0..196
    if (c >= NCHUNK) return;
    const int beg = rowstart[node];
    const int dc = deg[node];
    const float s = inv[node];
    const size_t off = (size_t)c * 2;

    float ax = 0.f, ay = 0.f, bx = 0.f, by = 0.f;
    float cx = 0.f, cy = 0.f, dx = 0.f, dy = 0.f;
    int j = 0;
    for (; j + 3 < dc; j += 4) {
        int n0 = elist[beg + j], n1 = elist[beg + j + 1];
        int n2 = elist[beg + j + 2], n3 = elist[beg + j + 3];
        float2 v0 = *(const float2*)(feat + (size_t)n0 * NODELEN + off);
        float2 v1 = *(const float2*)(feat + (size_t)n1 * NODELEN + off);
        float2 v2 = *(const float2*)(feat + (size_t)n2 * NODELEN + off);
        float2 v3 = *(const float2*)(feat + (size_t)n3 * NODELEN + off);
        ax += v0.x; ay += v0.y; bx += v1.x; by += v1.y;
        cx += v2.x; cy += v2.y; dx += v3.x; dy += v3.y;
    }
    for (; j < dc; ++j) {
        int n0 = elist[beg + j];
        float2 v0 = *(const float2*)(feat + (size_t)n0 * NODELEN + off);
        ax += v0.x; ay += v0.y;
    }
    float fx = (ax + bx + cx + dx) * s;
    float fy = (ay + by + cy + dy) * s;
    if (c == 0) fx = 0.f;
    unsigned out = ((unsigned)f2bf(fy) << 16) | (unsigned)f2bf(fx);
    *(unsigned*)(h1 + (size_t)node * NODELEN + off) = out;
}

__global__ __launch_bounds__(256) void gather2_emb(
        const float* __restrict__ feat, const unsigned* __restrict__ h1,
        const int* __restrict__ rowstart, const int* __restrict__ deg,
        const float* __restrict__ inv, const int* __restrict__ elist,
        float* __restrict__ emb) {
    const int node = blockIdx.x;
    const int c = threadIdx.x;          // chunk id, 0..196
    if (c >= NCHUNK) return;
    const int beg = rowstart[node];
    const int dc = deg[node];
    const float s = inv[node];

    float ax = 0.f, ay = 0.f, bx = 0.f, by = 0.f;
    float cx = 0.f, cy = 0.f, dx = 0.f, dy = 0.f;
    int j = 0;
    for (; j + 3 < dc; j += 4) {
        int n0 = elist[beg + j], n1 = elist[beg + j + 1];
        int n2 = elist[beg + j + 2], n3 = elist[beg + j + 3];
        unsigned u0 = h1[(size_t)n0 * NCHUNK + c];
        unsigned u1 = h1[(size_t)n1 * NCHUNK + c];
        unsigned u2 = h1[(size_t)n2 * NCHUNK + c];
        unsigned u3 = h1[(size_t)n3 * NCHUNK + c];
        ax += bf2f((unsigned short)u0); ay += bf2f((unsigned short)(u0 >> 16));
        bx += bf2f((unsigned short)u1); by += bf2f((unsigned short)(u1 >> 16));
        cx += bf2f((unsigned short)u2); cy += bf2f((unsigned short)(u2 >> 16));
        dx += bf2f((unsigned short)u3); dy += bf2f((unsigned short)(u3 >> 16));
    }
    for (; j < dc; ++j) {
        int n0 = elist[beg + j];
        unsigned u0 = h1[(size_t)n0 * NCHUNK + c];
        ax += bf2f((unsigned short)u0); ay += bf2f((unsigned short)(u0 >> 16));
    }
    float hx = (ax + bx + cx + dx) * s;
    float hy = (ay + by + cy + dy) * s;

    const float* fr = feat + (size_t)node * NODELEN;
    float* er = emb + (size_t)node * IN_DIM;
    float2 fv = *(const float2*)(fr + c * 2);
    if (c == 0) { fv.x = 0.f; hx = 0.f; }
    *(float2*)(er + c * 2) = fv;
    float2 hv; hv.x = hx; hv.y = hy;
    *(float2*)(er + NODELEN + c * 2) = hv;
}

// ---------------- fused weight pre-transpose ----------
__device__ __forceinline__ void tr_one(const float* W, unsigned short* Wt,
                                       int K, int N, int Kp, int idx) {
    int nrow = idx / Kp, k = idx - nrow * Kp;
    Wt[idx] = (k < K) ? f2bf(W[(size_t)k * N + nrow]) : (unsigned short)0;
}

#define T1E (192 * 800)
#define T2E (128 * 192)
#define T3E (192 * 128)
#define T4E (788 * 192)

__global__ void transpose_all(const float* __restrict__ W1, unsigned short* __restrict__ Wt1,
                              const float* __restrict__ W2, unsigned short* __restrict__ Wt2,
                              const float* __restrict__ W3, unsigned short* __restrict__ Wt3,
                              const float* __restrict__ W4, unsigned short* __restrict__ Wt4) {
    int idx = blockIdx.x * 256 + threadIdx.x;
    if (idx < T1E) { tr_one(W1, Wt1, IN_DIM, H2DIM, 800, idx); return; }
    idx -= T1E;
    if (idx < T2E) { tr_one(W2, Wt2, H2DIM, EMBDIM, 192, idx); return; }
    idx -= T2E;
    if (idx < T3E) { tr_one(W3, Wt3, EMBDIM, H2DIM, 128, idx); return; }
    idx -= T3E;
    if (idx < T4E) { tr_one(W4, Wt4, H2DIM, IN_DIM, 192, idx); return; }
}

// ---------------- fused MLP v3: B direct from global (L1/L2-hot), 3 barriers total --
// LDS only holds inter-stage activations (XY 24KB + EN 16KB = 40KB).
// Swizzled LDS addressing (in shorts): per-row bijection on 16B slots.
static __device__ __forceinline__ int xy_base(int r, int s) {           // XY[64][192], s=0..23
    int ph = (s & 24) | ((s ^ r) & 7);
    return r * 192 + (ph << 3);
}
static __device__ __forceinline__ int xy_addr_s(int r, int col) { return xy_base(r, col >> 3) + (col & 7); }
static __device__ __forceinline__ int en_base(int r, int s) {           // EN[64][128], s=0..15
    int ph = (s & 8) | ((s ^ r) & 7);
    return r * 128 + (ph << 3);
}
static __device__ __forceinline__ int en_addr_s(int r, int col) { return en_base(r, col >> 3) + (col & 7); }

static __device__ __forceinline__ unsigned short f2bf_fast(float f) {
    __hip_bfloat16 h = __float2bfloat16(f);
    union { __hip_bfloat16 h; unsigned short u; } c; c.h = h; return c.u;
}

struct A8 { float4 a, b; };

static __device__ __forceinline__ void load_a(A8 out[2], const float* __restrict__ emb,
                                              int m0, int wm, int lr, int lk, int M, int kt) {
    int c = kt * 32 + lk * 8;
    #pragma unroll
    for (int i = 0; i < 2; ++i) {
        int gm = m0 + wm * 32 + i * 16 + lr;
        const float* rp = emb + (size_t)gm * IN_DIM;
        bool v = gm < M;
        if (v && c + 8 <= IN_DIM) {
            out[i].a = *(const float4*)(rp + c);
            out[i].b = *(const float4*)(rp + c + 4);
        } else {
            float t[8];
            #pragma unroll
            for (int q = 0; q < 8; ++q) t[q] = (v && c + q < IN_DIM) ? rp[c + q] : 0.f;
            out[i].a = make_float4(t[0], t[1], t[2], t[3]);
            out[i].b = make_float4(t[4], t[5], t[6], t[7]);
        }
    }
}

static __device__ __forceinline__ bfrag cvt_a(const A8& x) {
    union { unsigned short u[8]; bfrag v; } pk;
    pk.u[0] = f2bf_fast(x.a.x); pk.u[1] = f2bf_fast(x.a.y);
    pk.u[2] = f2bf_fast(x.a.z); pk.u[3] = f2bf_fast(x.a.w);
    pk.u[4] = f2bf_fast(x.b.x); pk.u[5] = f2bf_fast(x.b.y);
    pk.u[6] = f2bf_fast(x.b.z); pk.u[7] = f2bf_fast(x.b.w);
    return pk.v;
}

__global__ __launch_bounds__(256, 3) void mlp_fused(
    const float* __restrict__ emb,
    const unsigned short* __restrict__ Wt1,  // [192][800]
    const unsigned short* __restrict__ Wt2,  // [128][192]
    const unsigned short* __restrict__ Wt3,  // [192][128]
    const unsigned short* __restrict__ Wt4,  // [788][192]
    const float* __restrict__ b1, const float* __restrict__ b2,
    const float* __restrict__ b3, const float* __restrict__ b4,
    float* __restrict__ encoded, float* __restrict__ decoded, int M)
{
    __shared__ unsigned short XY[64 * 192];  // 24 KB
    __shared__ unsigned short EN[64 * 128];  // 16 KB

    const int tid = threadIdx.x;
    const int wid = tid >> 6, l = tid & 63;
    const int wm = wid >> 1, wn = wid & 1;
    const int lr = l & 15, lk = l >> 4;
    const int m0 = blockIdx.x * 64;
    const bfrag zf = {0, 0, 0, 0, 0, 0, 0, 0};

    // ===== STAGE 1: x = relu(emb @ W1 + b1), K=788 (25 steps), N=192 ==========
    {
        f32x4 acc[2][6];
        #pragma unroll
        for (int i = 0; i < 2; ++i)
            #pragma unroll
            for (int j = 0; j < 6; ++j) acc[i][j] = (f32x4){0.f, 0.f, 0.f, 0.f};

        const unsigned short* wp[6];
        #pragma unroll
        for (int j = 0; j < 6; ++j)
            wp[j] = Wt1 + (size_t)(wn * 96 + j * 16 + lr) * 800 + lk * 8;

        #pragma unroll 5
        for (int kt = 0; kt < 25; ++kt) {
            A8 a[2];
            load_a(a, emb, m0, wm, lr, lk, M, kt);
            bfrag bf[6];
            #pragma unroll
            for (int j = 0; j < 6; ++j) bf[j] = *(const bfrag*)(wp[j] + kt * 32);
            bfrag af0 = cvt_a(a[0]), af1 = cvt_a(a[1]);
            #pragma unroll
            for (int j = 0; j < 6; ++j) {
                acc[0][j] = __builtin_amdgcn_mfma_f32_16x16x32_bf16(af0, bf[j], acc[0][j], 0, 0, 0);
                acc[1][j] = __builtin_amdgcn_mfma_f32_16x16x32_bf16(af1, bf[j], acc[1][j], 0, 0, 0);
            }
        }
        float bv[6];
        #pragma unroll
        for (int j = 0; j < 6; ++j) bv[j] = b1[wn * 96 + j * 16 + lr];
        #pragma unroll
        for (int i = 0; i < 2; ++i)
            #pragma unroll
            for (int j = 0; j < 6; ++j)
                #pragma unroll
                for (int r = 0; r < 4; ++r) {
                    int m = wm * 32 + i * 16 + lk * 4 + r;
                    int n1 = wn * 96 + j * 16 + lr;
                    XY[xy_addr_s(m, n1)] = f2bf_fast(fmaxf(acc[i][j][r] + bv[j], 0.f));
                }
    }
    __syncthreads();   // barrier 1: x visible

    // ===== STAGE 2: enc = x @ W2 + b2, K=192 (6 steps), N=128 =================
    {
        bfrag af2[6][2];
        #pragma unroll
        for (int q = 0; q < 6; ++q)
            #pragma unroll
            for (int i = 0; i < 2; ++i)
                af2[q][i] = *(const bfrag*)&XY[xy_base(wm * 32 + i * 16 + lr, q * 4 + lk)];

        f32x4 acc[2][4];
        #pragma unroll
        for (int i = 0; i < 2; ++i)
            #pragma unroll
            for (int j = 0; j < 4; ++j) acc[i][j] = (f32x4){0.f, 0.f, 0.f, 0.f};

        const unsigned short* wp[4];
        #pragma unroll
        for (int j = 0; j < 4; ++j)
            wp[j] = Wt2 + (size_t)(wn * 64 + j * 16 + lr) * 192 + lk * 8;

        #pragma unroll
        for (int kt = 0; kt < 6; ++kt) {
            bfrag bf[4];
            #pragma unroll
            for (int j = 0; j < 4; ++j) bf[j] = *(const bfrag*)(wp[j] + kt * 32);
            #pragma unroll
            for (int i = 0; i < 2; ++i)
                #pragma unroll
                for (int j = 0; j < 4; ++j)
                    acc[i][j] = __builtin_amdgcn_mfma_f32_16x16x32_bf16(af2[kt][i], bf[j], acc[i][j], 0, 0, 0);
        }
        float bv[4];
        #pragma unroll
        for (int j = 0; j < 4; ++j) bv[j] = b2[wn * 64 + j * 16 + lr];
        #pragma unroll
        for (int i = 0; i < 2; ++i)
            #pragma unroll
            for (int j = 0; j < 4; ++j)
                #pragma unroll
                for (int r = 0; r < 4; ++r) {
                    int m = wm * 32 + i * 16 + lk * 4 + r;
                    int nn = wn * 64 + j * 16 + lr;
                    float v = acc[i][j][r] + bv[j];
                    int gm = m0 + m;
                    if (gm < M) encoded[(size_t)gm * EMBDIM + nn] = v;
                    EN[en_addr_s(m, nn)] = f2bf_fast(v);
                }
    }
    __syncthreads();   // barrier 2: enc visible; x reads complete

    // ===== STAGE 3: y = relu(enc @ W3 + b3), K=128 (4 steps), N=192 ===========
    {
        bfrag af3[4][2];
        #pragma unroll
        for (int q = 0; q < 4; ++q)
            #pragma unroll
            for (int i = 0; i < 2; ++i)
                af3[q][i] = *(const bfrag*)&EN[en_base(wm * 32 + i * 16 + lr, q * 4 + lk)];

        f32x4 acc[2][6];
        #pragma unroll
        for (int i = 0; i < 2; ++i)
            #pragma unroll
            for (int j = 0; j < 6; ++j) acc[i][j] = (f32x4){0.f, 0.f, 0.f, 0.f};

        const unsigned short* wp[6];
        #pragma unroll
        for (int j = 0; j < 6; ++j)
            wp[j] = Wt3 + (size_t)(wn * 96 + j * 16 + lr) * 128 + lk * 8;

        #pragma unroll
        for (int kt = 0; kt < 4; ++kt) {
            bfrag bf[6];
            #pragma unroll
            for (int j = 0; j < 6; ++j) bf[j] = *(const bfrag*)(wp[j] + kt * 32);
            #pragma unroll
            for (int i = 0; i < 2; ++i)
                #pragma unroll
                for (int j = 0; j < 6; ++j)
                    acc[i][j] = __builtin_amdgcn_mfma_f32_16x16x32_bf16(af3[kt][i], bf[j], acc[i][j], 0, 0, 0);
        }
        // write y into XY: safe — all x reads finished before barrier 2
        float bv[6];
        #pragma unroll
        for (int j = 0; j < 6; ++j) bv[j] = b3[wn * 96 + j * 16 + lr];
        #pragma unroll
        for (int i = 0; i < 2; ++i)
            #pragma unroll
            for (int j = 0; j < 6; ++j)
                #pragma unroll
                for (int r = 0; r < 4; ++r) {
                    int m = wm * 32 + i * 16 + lk * 4 + r;
                    int nc = wn * 96 + j * 16 + lr;
                    XY[xy_addr_s(m, nc)] = f2bf_fast(fmaxf(acc[i][j][r] + bv[j], 0.f));
                }
    }
    __syncthreads();   // barrier 3: y visible

    // ===== STAGE 4: dec = y @ W4 + b4, K=192 (6 steps), N=788 (7 x 128) =======
    {
        bfrag af4[6][2];
        #pragma unroll
        for (int q = 0; q < 6; ++q)
            #pragma unroll
            for (int i = 0; i < 2; ++i)
                af4[q][i] = *(const bfrag*)&XY[xy_base(wm * 32 + i * 16 + lr, q * 4 + lk)];

        for (int nc = 0; nc < 7; ++nc) {
            f32x4 acc[2][4];
            #pragma unroll
            for (int i = 0; i < 2; ++i)
                #pragma unroll
                for (int j = 0; j < 4; ++j) acc[i][j] = (f32x4){0.f, 0.f, 0.f, 0.f};

            const int colb = nc * 128 + wn * 64 + lr;
            #pragma unroll
            for (int kt = 0; kt < 6; ++kt) {
                bfrag bf[4];
                #pragma unroll
                for (int j = 0; j < 4; ++j) {
                    int row = colb + j * 16;
                    bf[j] = (row < IN_DIM)
                        ? *(const bfrag*)(Wt4 + (size_t)row * 192 + kt * 32 + lk * 8) : zf;
                }
                #pragma unroll
                for (int i = 0; i < 2; ++i)
                    #pragma unroll
                    for (int j = 0; j < 4; ++j)
                        acc[i][j] = __builtin_amdgcn_mfma_f32_16x16x32_bf16(af4[kt][i], bf[j], acc[i][j], 0, 0, 0);
            }

            float bv[4];
            #pragma unroll
            for (int j = 0; j < 4; ++j) {
                int nn = colb + j * 16;
                bv[j] = (nn < IN_DIM) ? b4[nn] : 0.f;
            }
            #pragma unroll
            for (int i = 0; i < 2; ++i)
                #pragma unroll
                for (int j = 0; j < 4; ++j)
                    #pragma unroll
                    for (int r = 0; r < 4; ++r) {
                        int gm = m0 + wm * 32 + i * 16 + lk * 4 + r;
                        int nn = colb + j * 16;
                        if (gm < M && nn < IN_DIM)
                            decoded[(size_t)gm * IN_DIM + nn] = acc[i][j][r] + bv[j];
                    }
        }
    }
}

// ---------------- launch ----------------

extern "C" void kernel_launch(void* const* d_in, const int* in_sizes, int n_in,
                              void* d_out, int out_size, void* d_ws, size_t ws_size,
                              hipStream_t stream) {
    const float* features = (const float*)d_in[0];
    const int*   src      = (const int*)d_in[1];
    const int*   dst      = (const int*)d_in[2];
    const float* W_enc1   = (const float*)d_in[3];
    const float* b_enc1   = (const float*)d_in[4];
    const float* W_enc3   = (const float*)d_in[5];
    const float* b_enc3   = (const float*)d_in[6];
    const float* W_dec1   = (const float*)d_in[7];
    const float* b_dec1   = (const float*)d_in[8];
    const float* W_dec3   = (const float*)d_in[9];
    const float* b_dec3   = (const float*)d_in[10];

    const int n = in_sizes[0] / NODELEN;  // 50000
    const int e = in_sizes[1];            // 200000

    // d_out layout: encoded [n,128] | decoded [n,788] | emb [n,788]
    float* encoded = (float*)d_out;
    float* decoded = encoded + (size_t)n * EMBDIM;
    float* emb     = decoded + (size_t)n * IN_DIM;

    // ws layout (bytes) — total < 43 MB
    char* ws = (char*)d_ws;
    unsigned short* h1  = (unsigned short*)(ws + 0);          // n*394*2 = 39.4 MB
    unsigned short* Wt1 = (unsigned short*)(ws + 40000000);   // 192*800*2
    unsigned short* Wt2 = (unsigned short*)(ws + 40400000);   // 128*192*2
    unsigned short* Wt3 = (unsigned short*)(ws + 40500000);   // 192*128*2
    unsigned short* Wt4 = (unsigned short*)(ws + 40600000);   // 788*192*2
    float* inv          = (float*)(ws + 41000000);            // n*4
    int*   deg          = (int*)  (ws + 41200000);
    int*   rowstart     = (int*)  (ws + 41400000);
    int*   cursor       = (int*)  (ws + 41600000);
    int*   elist        = (int*)  (ws + 41800000);            // e*4
    int*   bsum         = (int*)  (ws + 42600000);

    const int nb = (n + 255) / 256;
    const int eb = (e + 255) / 256;

    transpose_all<<<(T1E + T2E + T3E + T4E + 255) / 256, 256, 0, stream>>>(
        W_enc1, Wt1, W_enc3, Wt2, W_dec1, Wt3, W_dec3, Wt4);

    hipMemsetAsync(deg, 0, (size_t)n * sizeof(int), stream);
    count_deg<<<eb, 256, 0, stream>>>(dst, deg, e);
    block_sum<<<nb, 256, 0, stream>>>(deg, bsum, n);
    scan_bsums<<<1, 256, 0, stream>>>(bsum, nb);
    block_scan<<<nb, 256, 0, stream>>>(deg, bsum, rowstart, cursor, inv, n);
    fill_edges<<<eb, 256, 0, stream>>>(src, dst, cursor, elist, e);

    gather1<<<n, 256, 0, stream>>>(features, rowstart, deg, inv, elist, h1);
    gather2_emb<<<n, 256, 0, stream>>>(features, (const unsigned*)h1, rowstart, deg,
                                       inv, elist, emb);

    const int MB = (n + 63) / 64;  // 782
    mlp_fused<<<MB, 256, 0, stream>>>(emb, Wt1, Wt2, Wt3, Wt4,
                                      b_enc1, b_enc3, b_dec1, b_dec3,
                                      encoded, decoded, n);
}

// Round 8
// 350.674 us; speedup vs baseline: 1.1842x; 1.1842x over previous
//
#include <hip/hip_runtime.h>
#include <hip/hip_bf16.h>

#define NODELEN 394
#define IN_DIM 788
#define H2DIM 192
#define EMBDIM 128
#define NCHUNK 197   // 394 elems = 197 x (float2 | uint-packed-bf16x2)

typedef __attribute__((ext_vector_type(4))) float f32x4;
typedef __attribute__((ext_vector_type(8))) short bfrag;  // 8 bf16 = 4 VGPRs

static __device__ __forceinline__ unsigned short f2bf(float f) {
    union { float f; unsigned u; } v; v.f = f;
    unsigned r = v.u + 0x7FFFu + ((v.u >> 16) & 1u);  // round-to-nearest-even
    return (unsigned short)(r >> 16);
}
static __device__ __forceinline__ float bf2f(unsigned short h) {
    union { unsigned u; float f; } v; v.u = ((unsigned)h) << 16;
    return v.f;
}

// ---------------- CSR build ----------------

__global__ void count_deg(const int* __restrict__ dst, int* __restrict__ deg, int e) {
    int i = blockIdx.x * blockDim.x + threadIdx.x;
    if (i < e) atomicAdd(&deg[dst[i]], 1);
}

__global__ void block_sum(const int* __restrict__ deg, int* __restrict__ bsum, int n) {
    __shared__ int s[256];
    int t = threadIdx.x;
    int i = blockIdx.x * 256 + t;
    s[t] = (i < n) ? deg[i] : 0;
    __syncthreads();
    for (int d = 128; d > 0; d >>= 1) {
        if (t < d) s[t] += s[t + d];
        __syncthreads();
    }
    if (t == 0) bsum[blockIdx.x] = s[0];
}

__global__ void scan_bsums(int* bsum, int nb) {
    __shared__ int s[256];
    int t = threadIdx.x;
    int x0 = (t < nb) ? bsum[t] : 0;
    s[t] = x0;
    __syncthreads();
    for (int d = 1; d < 256; d <<= 1) {
        int u = (t >= d) ? s[t - d] : 0;
        __syncthreads();
        s[t] += u;
        __syncthreads();
    }
    if (t < nb) bsum[t] = s[t] - x0;
}

// also emits inv = 1/max(deg,1)
__global__ void block_scan(const int* __restrict__ deg, const int* __restrict__ boff,
                           int* __restrict__ rowstart, int* __restrict__ cursor,
                           float* __restrict__ inv, int n) {
    __shared__ int s[256];
    int t = threadIdx.x;
    int i = blockIdx.x * 256 + t;
    int x0 = (i < n) ? deg[i] : 0;
    s[t] = x0;
    __syncthreads();
    for (int d = 1; d < 256; d <<= 1) {
        int u = (t >= d) ? s[t - d] : 0;
        __syncthreads();
        s[t] += u;
        __syncthreads();
    }
    if (i < n) {
        int r = boff[blockIdx.x] + s[t] - x0;
        rowstart[i] = r;
        cursor[i] = r;
        inv[i] = 1.0f / fmaxf((float)x0, 1.0f);
    }
}

__global__ void fill_edges(const int* __restrict__ src, const int* __restrict__ dst,
                           int* __restrict__ cursor, int* __restrict__ elist, int e) {
    int i = blockIdx.x * blockDim.x + threadIdx.x;
    if (i < e) {
        int p = atomicAdd(&cursor[dst[i]], 1);
        elist[p] = src[i];
    }
}

// ---------------- aggregation (gather, float2-vectorized, 4-deep neighbor ILP) ----

__global__ __launch_bounds__(256) void gather1(
        const float* __restrict__ feat, const int* __restrict__ rowstart,
        const int* __restrict__ deg, const float* __restrict__ inv,
        const int* __restrict__ elist, unsigned short* __restrict__ h1) {
    const int node = blockIdx.x;
    const int c = threadIdx.x;          // float2 chunk id, 0..196
    if (c >= NCHUNK) return;
    const int beg = rowstart[node];
    const int dc = deg[node];
    const float s = inv[node];
    const size_t off = (size_t)c * 2;

    float ax = 0.f, ay = 0.f, bx = 0.f, by = 0.f;
    float cx = 0.f, cy = 0.f, dx = 0.f, dy = 0.f;
    int j = 0;
    for (; j + 3 < dc; j += 4) {
        int n0 = elist[beg + j], n1 = elist[beg + j + 1];
        int n2 = elist[beg + j + 2], n3 = elist[beg + j + 3];
        float2 v0 = *(const float2*)(feat + (size_t)n0 * NODELEN + off);
        float2 v1 = *(const float2*)(feat + (size_t)n1 * NODELEN + off);
        float2 v2 = *(const float2*)(feat + (size_t)n2 * NODELEN + off);
        float2 v3 = *(const float2*)(feat + (size_t)n3 * NODELEN + off);
        ax += v0.x; ay += v0.y; bx += v1.x; by += v1.y;
        cx += v2.x; cy += v2.y; dx += v3.x; dy += v3.y;
    }
    for (; j < dc; ++j) {
        int n0 = elist[beg + j];
        float2 v0 = *(const float2*)(feat + (size_t)n0 * NODELEN + off);
        ax += v0.x; ay += v0.y;
    }
    float fx = (ax + bx + cx + dx) * s;
    float fy = (ay + by + cy + dy) * s;
    if (c == 0) fx = 0.f;
    unsigned out = ((unsigned)f2bf(fy) << 16) | (unsigned)f2bf(fx);
    *(unsigned*)(h1 + (size_t)node * NODELEN + off) = out;
}

__global__ __launch_bounds__(256) void gather2_emb(
        const float* __restrict__ feat, const unsigned* __restrict__ h1,
        const int* __restrict__ rowstart, const int* __restrict__ deg,
        const float* __restrict__ inv, const int* __restrict__ elist,
        float* __restrict__ emb) {
    const int node = blockIdx.x;
    const int c = threadIdx.x;          // chunk id, 0..196
    if (c >= NCHUNK) return;
    const int beg = rowstart[node];
    const int dc = deg[node];
    const float s = inv[node];

    float ax = 0.f, ay = 0.f, bx = 0.f, by = 0.f;
    float cx = 0.f, cy = 0.f, dx = 0.f, dy = 0.f;
    int j = 0;
    for (; j + 3 < dc; j += 4) {
        int n0 = elist[beg + j], n1 = elist[beg + j + 1];
        int n2 = elist[beg + j + 2], n3 = elist[beg + j + 3];
        unsigned u0 = h1[(size_t)n0 * NCHUNK + c];
        unsigned u1 = h1[(size_t)n1 * NCHUNK + c];
        unsigned u2 = h1[(size_t)n2 * NCHUNK + c];
        unsigned u3 = h1[(size_t)n3 * NCHUNK + c];
        ax += bf2f((unsigned short)u0); ay += bf2f((unsigned short)(u0 >> 16));
        bx += bf2f((unsigned short)u1); by += bf2f((unsigned short)(u1 >> 16));
        cx += bf2f((unsigned short)u2); cy += bf2f((unsigned short)(u2 >> 16));
        dx += bf2f((unsigned short)u3); dy += bf2f((unsigned short)(u3 >> 16));
    }
    for (; j < dc; ++j) {
        int n0 = elist[beg + j];
        unsigned u0 = h1[(size_t)n0 * NCHUNK + c];
        ax += bf2f((unsigned short)u0); ay += bf2f((unsigned short)(u0 >> 16));
    }
    float hx = (ax + bx + cx + dx) * s;
    float hy = (ay + by + cy + dy) * s;

    const float* fr = feat + (size_t)node * NODELEN;
    float* er = emb + (size_t)node * IN_DIM;
    float2 fv = *(const float2*)(fr + c * 2);
    if (c == 0) { fv.x = 0.f; hx = 0.f; }
    *(float2*)(er + c * 2) = fv;
    float2 hv; hv.x = hx; hv.y = hy;
    *(float2*)(er + NODELEN + c * 2) = hv;
}

// ---------------- fused weight pre-transpose ----------
__device__ __forceinline__ void tr_one(const float* W, unsigned short* Wt,
                                       int K, int N, int Kp, int idx) {
    int nrow = idx / Kp, k = idx - nrow * Kp;
    Wt[idx] = (k < K) ? f2bf(W[(size_t)k * N + nrow]) : (unsigned short)0;
}

#define T1E (192 * 800)
#define T2E (128 * 192)
#define T3E (192 * 128)
#define T4E (788 * 192)

__global__ void transpose_all(const float* __restrict__ W1, unsigned short* __restrict__ Wt1,
                              const float* __restrict__ W2, unsigned short* __restrict__ Wt2,
                              const float* __restrict__ W3, unsigned short* __restrict__ Wt3,
                              const float* __restrict__ W4, unsigned short* __restrict__ Wt4) {
    int idx = blockIdx.x * 256 + threadIdx.x;
    if (idx < T1E) { tr_one(W1, Wt1, IN_DIM, H2DIM, 800, idx); return; }
    idx -= T1E;
    if (idx < T2E) { tr_one(W2, Wt2, H2DIM, EMBDIM, 192, idx); return; }
    idx -= T2E;
    if (idx < T3E) { tr_one(W3, Wt3, EMBDIM, H2DIM, 128, idx); return; }
    idx -= T3E;
    if (idx < T4E) { tr_one(W4, Wt4, H2DIM, IN_DIM, 192, idx); return; }
}

// ---------------- fused MLP, split in two kernels, dbuf-B (1 barrier/K-step) ------
// Swizzled LDS addressing (in shorts): per-row bijection on 16B slots.
static __device__ __forceinline__ int bs_addr(int r, int s) {           // Bs[192][32], s=0..3
    return r * 32 + ((s ^ ((r >> 1) & 3)) << 3);
}
static __device__ __forceinline__ int xy_base(int r, int s) {           // XY[64][192], s=0..23
    int ph = (s & 24) | ((s ^ r) & 7);
    return r * 192 + (ph << 3);
}
static __device__ __forceinline__ int xy_addr_s(int r, int col) { return xy_base(r, col >> 3) + (col & 7); }

static __device__ __forceinline__ unsigned short f2bf_fast(float f) {
    __hip_bfloat16 h = __float2bfloat16(f);
    union { __hip_bfloat16 h; unsigned short u; } c; c.h = h; return c.u;
}

struct A8 { float4 a, b; };

static __device__ __forceinline__ void load_a(A8 out[2], const float* __restrict__ emb,
                                              int m0, int wm, int lr, int lk, int M, int kt) {
    int c = kt * 32 + lk * 8;
    #pragma unroll
    for (int i = 0; i < 2; ++i) {
        int gm = m0 + wm * 32 + i * 16 + lr;
        const float* rp = emb + (size_t)gm * IN_DIM;
        bool v = gm < M;
        if (v && c + 8 <= IN_DIM) {
            out[i].a = *(const float4*)(rp + c);
            out[i].b = *(const float4*)(rp + c + 4);
        } else {
            float t[8];
            #pragma unroll
            for (int q = 0; q < 8; ++q) t[q] = (v && c + q < IN_DIM) ? rp[c + q] : 0.f;
            out[i].a = make_float4(t[0], t[1], t[2], t[3]);
            out[i].b = make_float4(t[4], t[5], t[6], t[7]);
        }
    }
}

static __device__ __forceinline__ bfrag cvt_a(const A8& x) {
    union { unsigned short u[8]; bfrag v; } pk;
    pk.u[0] = f2bf_fast(x.a.x); pk.u[1] = f2bf_fast(x.a.y);
    pk.u[2] = f2bf_fast(x.a.z); pk.u[3] = f2bf_fast(x.a.w);
    pk.u[4] = f2bf_fast(x.b.x); pk.u[5] = f2bf_fast(x.b.y);
    pk.u[6] = f2bf_fast(x.b.z); pk.u[7] = f2bf_fast(x.b.w);
    return pk.v;
}

// ===== kernel A: stage1+2  emb -> x(lds) -> encoded(f32) + enc16(bf16) ==========
__global__ __launch_bounds__(256, 3) void mlp12(
    const float* __restrict__ emb,
    const unsigned short* __restrict__ Wt1,  // [192][800]
    const unsigned short* __restrict__ Wt2,  // [128][192]
    const float* __restrict__ b1, const float* __restrict__ b2,
    float* __restrict__ encoded, unsigned short* __restrict__ enc16, int M)
{
    __shared__ unsigned short XY[64 * 192];      // 24 KB
    __shared__ unsigned short Bs[2][192 * 32];   // 24 KB (ping-pong)

    const int tid = threadIdx.x;
    const int wid = tid >> 6, l = tid & 63;
    const int wm = wid >> 1, wn = wid & 1;
    const int lr = l & 15, lk = l >> 4;
    const int m0 = blockIdx.x * 64;

    const int r0 = tid >> 2, s0 = tid & 3;
    const int r1 = (tid + 256) >> 2;
    const int r2 = (tid + 512) >> 2;
    const int bw0 = bs_addr(r0, s0);
    const int bw1 = bs_addr(r1, s0);
    const int bw2 = bs_addr(r2, s0);
    int brd6[6], brd4[4];
    #pragma unroll
    for (int j = 0; j < 6; ++j) brd6[j] = bs_addr(wn * 96 + j * 16 + lr, lk);
    #pragma unroll
    for (int j = 0; j < 4; ++j) brd4[j] = bs_addr(wn * 64 + j * 16 + lr, lk);

    // ---- STAGE 1: K=788 (25 steps), N=192, dbuf B, 1 barrier/step ----
    {
        f32x4 acc[2][6];
        #pragma unroll
        for (int i = 0; i < 2; ++i)
            #pragma unroll
            for (int j = 0; j < 6; ++j) acc[i][j] = (f32x4){0.f, 0.f, 0.f, 0.f};

        A8 aC[2], aN[2];
        bfrag bC[3], bN[3];
        load_a(aC, emb, m0, wm, lr, lk, M, 0);
        bC[0] = *(const bfrag*)(Wt1 + (size_t)r0 * 800 + s0 * 8);
        bC[1] = *(const bfrag*)(Wt1 + (size_t)r1 * 800 + s0 * 8);
        bC[2] = *(const bfrag*)(Wt1 + (size_t)r2 * 800 + s0 * 8);

        #pragma unroll 5
        for (int kt = 0; kt < 25; ++kt) {
            unsigned short* B = Bs[kt & 1];
            *(bfrag*)&B[bw0] = bC[0];
            *(bfrag*)&B[bw1] = bC[1];
            *(bfrag*)&B[bw2] = bC[2];
            if (kt < 24) {
                int k0 = (kt + 1) * 32;
                load_a(aN, emb, m0, wm, lr, lk, M, kt + 1);
                bN[0] = *(const bfrag*)(Wt1 + (size_t)r0 * 800 + k0 + s0 * 8);
                bN[1] = *(const bfrag*)(Wt1 + (size_t)r1 * 800 + k0 + s0 * 8);
                bN[2] = *(const bfrag*)(Wt1 + (size_t)r2 * 800 + k0 + s0 * 8);
            }
            __syncthreads();   // B[kt] ready; next write goes to other buffer
            bfrag af0 = cvt_a(aC[0]), af1 = cvt_a(aC[1]);
            bfrag bf[6];
            #pragma unroll
            for (int j = 0; j < 6; ++j) bf[j] = *(const bfrag*)&B[brd6[j]];
            #pragma unroll
            for (int j = 0; j < 6; ++j) {
                acc[0][j] = __builtin_amdgcn_mfma_f32_16x16x32_bf16(af0, bf[j], acc[0][j], 0, 0, 0);
                acc[1][j] = __builtin_amdgcn_mfma_f32_16x16x32_bf16(af1, bf[j], acc[1][j], 0, 0, 0);
            }
            if (kt < 24) {
                aC[0] = aN[0]; aC[1] = aN[1];
                bC[0] = bN[0]; bC[1] = bN[1]; bC[2] = bN[2];
            }
        }
        float bv[6];
        #pragma unroll
        for (int j = 0; j < 6; ++j) bv[j] = b1[wn * 96 + j * 16 + lr];
        #pragma unroll
        for (int i = 0; i < 2; ++i)
            #pragma unroll
            for (int j = 0; j < 6; ++j)
                #pragma unroll
                for (int r = 0; r < 4; ++r) {
                    int m = wm * 32 + i * 16 + lk * 4 + r;
                    int n1 = wn * 96 + j * 16 + lr;
                    XY[xy_addr_s(m, n1)] = f2bf_fast(fmaxf(acc[i][j][r] + bv[j], 0.f));
                }
    }
    __syncthreads();   // x visible

    // ---- STAGE 2: K=192 (6 steps), N=128, dbuf B ----
    {
        bfrag af2[6][2];
        #pragma unroll
        for (int q = 0; q < 6; ++q)
            #pragma unroll
            for (int i = 0; i < 2; ++i)
                af2[q][i] = *(const bfrag*)&XY[xy_base(wm * 32 + i * 16 + lr, q * 4 + lk)];

        f32x4 acc[2][4];
        #pragma unroll
        for (int i = 0; i < 2; ++i)
            #pragma unroll
            for (int j = 0; j < 4; ++j) acc[i][j] = (f32x4){0.f, 0.f, 0.f, 0.f};

        bfrag bC[2], bN[2];
        bC[0] = *(const bfrag*)(Wt2 + (size_t)r0 * 192 + s0 * 8);
        bC[1] = *(const bfrag*)(Wt2 + (size_t)r1 * 192 + s0 * 8);

        #pragma unroll
        for (int kt = 0; kt < 6; ++kt) {
            unsigned short* B = Bs[kt & 1];
            *(bfrag*)&B[bw0] = bC[0];
            *(bfrag*)&B[bw1] = bC[1];
            if (kt < 5) {
                int k0 = (kt + 1) * 32;
                bN[0] = *(const bfrag*)(Wt2 + (size_t)r0 * 192 + k0 + s0 * 8);
                bN[1] = *(const bfrag*)(Wt2 + (size_t)r1 * 192 + k0 + s0 * 8);
            }
            __syncthreads();
            bfrag bf[4];
            #pragma unroll
            for (int j = 0; j < 4; ++j) bf[j] = *(const bfrag*)&B[brd4[j]];
            #pragma unroll
            for (int i = 0; i < 2; ++i)
                #pragma unroll
                for (int j = 0; j < 4; ++j)
                    acc[i][j] = __builtin_amdgcn_mfma_f32_16x16x32_bf16(af2[kt][i], bf[j], acc[i][j], 0, 0, 0);
            if (kt < 5) { bC[0] = bN[0]; bC[1] = bN[1]; }
        }

        float bv[4];
        #pragma unroll
        for (int j = 0; j < 4; ++j) bv[j] = b2[wn * 64 + j * 16 + lr];
        #pragma unroll
        for (int i = 0; i < 2; ++i)
            #pragma unroll
            for (int j = 0; j < 4; ++j)
                #pragma unroll
                for (int r = 0; r < 4; ++r) {
                    int m = wm * 32 + i * 16 + lk * 4 + r;
                    int nn = wn * 64 + j * 16 + lr;
                    float v = acc[i][j][r] + bv[j];
                    int gm = m0 + m;
                    if (gm < M) {
                        encoded[(size_t)gm * EMBDIM + nn] = v;
                        enc16[(size_t)gm * EMBDIM + nn] = f2bf_fast(v);
                    }
                }
    }
}

// ===== kernel B: stage3+4  enc16 -> y(lds) -> decoded(f32) ======================
__global__ __launch_bounds__(256, 3) void mlp34(
    const unsigned short* __restrict__ enc16,
    const unsigned short* __restrict__ Wt3,  // [192][128]
    const unsigned short* __restrict__ Wt4,  // [788][192]
    const float* __restrict__ b3, const float* __restrict__ b4,
    float* __restrict__ decoded, int M)
{
    __shared__ unsigned short XY[64 * 192];      // 24 KB (y)
    __shared__ unsigned short Bs[2][192 * 32];   // 24 KB

    const int tid = threadIdx.x;
    const int wid = tid >> 6, l = tid & 63;
    const int wm = wid >> 1, wn = wid & 1;
    const int lr = l & 15, lk = l >> 4;
    const int m0 = blockIdx.x * 64;
    const bfrag zf = {0, 0, 0, 0, 0, 0, 0, 0};

    const int r0 = tid >> 2, s0 = tid & 3;
    const int r1 = (tid + 256) >> 2;
    const int r2 = (tid + 512) >> 2;
    const int bw0 = bs_addr(r0, s0);
    const int bw1 = bs_addr(r1, s0);
    const int bw2 = bs_addr(r2, s0);
    int brd6[6];
    #pragma unroll
    for (int j = 0; j < 6; ++j) brd6[j] = bs_addr(wn * 96 + j * 16 + lr, lk);

    // ---- STAGE 3: y = relu(enc @ W3 + b3), K=128 (4 steps), N=192 ----
    {
        // A-frags straight from global enc16 (coalesced; no LDS, no barrier)
        bfrag af3[4][2];
        #pragma unroll
        for (int q = 0; q < 4; ++q)
            #pragma unroll
            for (int i = 0; i < 2; ++i) {
                int gm = m0 + wm * 32 + i * 16 + lr;
                af3[q][i] = (gm < M)
                    ? *(const bfrag*)(enc16 + (size_t)gm * EMBDIM + q * 32 + lk * 8) : zf;
            }

        f32x4 acc[2][6];
        #pragma unroll
        for (int i = 0; i < 2; ++i)
            #pragma unroll
            for (int j = 0; j < 6; ++j) acc[i][j] = (f32x4){0.f, 0.f, 0.f, 0.f};

        bfrag bC[3], bN[3];
        bC[0] = *(const bfrag*)(Wt3 + (size_t)r0 * 128 + s0 * 8);
        bC[1] = *(const bfrag*)(Wt3 + (size_t)r1 * 128 + s0 * 8);
        bC[2] = *(const bfrag*)(Wt3 + (size_t)r2 * 128 + s0 * 8);

        #pragma unroll
        for (int kt = 0; kt < 4; ++kt) {
            unsigned short* B = Bs[kt & 1];
            *(bfrag*)&B[bw0] = bC[0];
            *(bfrag*)&B[bw1] = bC[1];
            *(bfrag*)&B[bw2] = bC[2];
            if (kt < 3) {
                int k0 = (kt + 1) * 32;
                bN[0] = *(const bfrag*)(Wt3 + (size_t)r0 * 128 + k0 + s0 * 8);
                bN[1] = *(const bfrag*)(Wt3 + (size_t)r1 * 128 + k0 + s0 * 8);
                bN[2] = *(const bfrag*)(Wt3 + (size_t)r2 * 128 + k0 + s0 * 8);
            }
            __syncthreads();
            bfrag bf[6];
            #pragma unroll
            for (int j = 0; j < 6; ++j) bf[j] = *(const bfrag*)&B[brd6[j]];
            #pragma unroll
            for (int i = 0; i < 2; ++i)
                #pragma unroll
                for (int j = 0; j < 6; ++j)
                    acc[i][j] = __builtin_amdgcn_mfma_f32_16x16x32_bf16(af3[kt][i], bf[j], acc[i][j], 0, 0, 0);
            if (kt < 3) { bC[0] = bN[0]; bC[1] = bN[1]; bC[2] = bN[2]; }
        }

        float bv[6];
        #pragma unroll
        for (int j = 0; j < 6; ++j) bv[j] = b3[wn * 96 + j * 16 + lr];
        #pragma unroll
        for (int i = 0; i < 2; ++i)
            #pragma unroll
            for (int j = 0; j < 6; ++j)
                #pragma unroll
                for (int r = 0; r < 4; ++r) {
                    int m = wm * 32 + i * 16 + lk * 4 + r;
                    int nc = wn * 96 + j * 16 + lr;
                    XY[xy_addr_s(m, nc)] = f2bf_fast(fmaxf(acc[i][j][r] + bv[j], 0.f));
                }
    }
    __syncthreads();   // y visible

    // ---- STAGE 4: dec = y @ W4 + b4, K=192 (6 steps), N=788 (5 x 192) ----
    {
        bfrag af4[6][2];
        #pragma unroll
        for (int q = 0; q < 6; ++q)
            #pragma unroll
            for (int i = 0; i < 2; ++i)
                af4[q][i] = *(const bfrag*)&XY[xy_base(wm * 32 + i * 16 + lr, q * 4 + lk)];

        bfrag bC[3], bN[3];
        // t=0: chunk 0, kt 0; rows r0,r1,r2 < 788
        bC[0] = *(const bfrag*)(Wt4 + (size_t)r0 * 192 + s0 * 8);
        bC[1] = *(const bfrag*)(Wt4 + (size_t)r1 * 192 + s0 * 8);
        bC[2] = *(const bfrag*)(Wt4 + (size_t)r2 * 192 + s0 * 8);

        for (int nc = 0; nc < 5; ++nc) {
            f32x4 acc[2][6];
            #pragma unroll
            for (int i = 0; i < 2; ++i)
                #pragma unroll
                for (int j = 0; j < 6; ++j) acc[i][j] = (f32x4){0.f, 0.f, 0.f, 0.f};

            #pragma unroll
            for (int kt = 0; kt < 6; ++kt) {
                const int t = nc * 6 + kt;
                unsigned short* B = Bs[t & 1];
                *(bfrag*)&B[bw0] = bC[0];
                *(bfrag*)&B[bw1] = bC[1];
                *(bfrag*)&B[bw2] = bC[2];
                if (t < 29) {
                    int nn = (kt < 5) ? nc : nc + 1;
                    int nk = (kt < 5) ? (kt + 1) * 32 : 0;
                    int g0 = nn * 192 + r0, g1 = nn * 192 + r1, g2 = nn * 192 + r2;
                    bN[0] = (g0 < IN_DIM) ? *(const bfrag*)(Wt4 + (size_t)g0 * 192 + nk + s0 * 8) : zf;
                    bN[1] = (g1 < IN_DIM) ? *(const bfrag*)(Wt4 + (size_t)g1 * 192 + nk + s0 * 8) : zf;
                    bN[2] = (g2 < IN_DIM) ? *(const bfrag*)(Wt4 + (size_t)g2 * 192 + nk + s0 * 8) : zf;
                }
                __syncthreads();
                bfrag bf[6];
                #pragma unroll
                for (int j = 0; j < 6; ++j) bf[j] = *(const bfrag*)&B[brd6[j]];
                #pragma unroll
                for (int i = 0; i < 2; ++i)
                    #pragma unroll
                    for (int j = 0; j < 6; ++j)
                        acc[i][j] = __builtin_amdgcn_mfma_f32_16x16x32_bf16(af4[kt][i], bf[j], acc[i][j], 0, 0, 0);
                bC[0] = bN[0]; bC[1] = bN[1]; bC[2] = bN[2];
            }

            float bv[6];
            #pragma unroll
            for (int j = 0; j < 6; ++j) {
                int nn = nc * 192 + wn * 96 + j * 16 + lr;
                bv[j] = (nn < IN_DIM) ? b4[nn] : 0.f;
            }
            #pragma unroll
            for (int i = 0; i < 2; ++i)
                #pragma unroll
                for (int j = 0; j < 6; ++j)
                    #pragma unroll
                    for (int r = 0; r < 4; ++r) {
                        int gm = m0 + wm * 32 + i * 16 + lk * 4 + r;
                        int nn = nc * 192 + wn * 96 + j * 16 + lr;
                        if (gm < M && nn < IN_DIM)
                            decoded[(size_t)gm * IN_DIM + nn] = acc[i][j][r] + bv[j];
                    }
        }
    }
}

// ---------------- launch ----------------

extern "C" void kernel_launch(void* const* d_in, const int* in_sizes, int n_in,
                              void* d_out, int out_size, void* d_ws, size_t ws_size,
                              hipStream_t stream) {
    const float* features = (const float*)d_in[0];
    const int*   src      = (const int*)d_in[1];
    const int*   dst      = (const int*)d_in[2];
    const float* W_enc1   = (const float*)d_in[3];
    const float* b_enc1   = (const float*)d_in[4];
    const float* W_enc3   = (const float*)d_in[5];
    const float* b_enc3   = (const float*)d_in[6];
    const float* W_dec1   = (const float*)d_in[7];
    const float* b_dec1   = (const float*)d_in[8];
    const float* W_dec3   = (const float*)d_in[9];
    const float* b_dec3   = (const float*)d_in[10];

    const int n = in_sizes[0] / NODELEN;  // 50000
    const int e = in_sizes[1];            // 200000

    // d_out layout: encoded [n,128] | decoded [n,788] | emb [n,788]
    float* encoded = (float*)d_out;
    float* decoded = encoded + (size_t)n * EMBDIM;
    float* emb     = decoded + (size_t)n * IN_DIM;

    // ws layout (bytes) — h1 region reused by enc16 after gather2 completes
    char* ws = (char*)d_ws;
    unsigned short* h1    = (unsigned short*)(ws + 0);        // n*394*2 = 39.4 MB
    unsigned short* enc16 = (unsigned short*)(ws + 0);        // n*128*2 = 12.8 MB (after gathers)
    unsigned short* Wt1 = (unsigned short*)(ws + 40000000);   // 192*800*2
    unsigned short* Wt2 = (unsigned short*)(ws + 40400000);   // 128*192*2
    unsigned short* Wt3 = (unsigned short*)(ws + 40500000);   // 192*128*2
    unsigned short* Wt4 = (unsigned short*)(ws + 40600000);   // 788*192*2
    float* inv          = (float*)(ws + 41000000);            // n*4
    int*   deg          = (int*)  (ws + 41200000);
    int*   rowstart     = (int*)  (ws + 41400000);
    int*   cursor       = (int*)  (ws + 41600000);
    int*   elist        = (int*)  (ws + 41800000);            // e*4
    int*   bsum         = (int*)  (ws + 42600000);

    const int nb = (n + 255) / 256;
    const int eb = (e + 255) / 256;

    transpose_all<<<(T1E + T2E + T3E + T4E + 255) / 256, 256, 0, stream>>>(
        W_enc1, Wt1, W_enc3, Wt2, W_dec1, Wt3, W_dec3, Wt4);

    hipMemsetAsync(deg, 0, (size_t)n * sizeof(int), stream);
    count_deg<<<eb, 256, 0, stream>>>(dst, deg, e);
    block_sum<<<nb, 256, 0, stream>>>(deg, bsum, n);
    scan_bsums<<<1, 256, 0, stream>>>(bsum, nb);
    block_scan<<<nb, 256, 0, stream>>>(deg, bsum, rowstart, cursor, inv, n);
    fill_edges<<<eb, 256, 0, stream>>>(src, dst, cursor, elist, e);

    gather1<<<n, 256, 0, stream>>>(features, rowstart, deg, inv, elist, h1);
    gather2_emb<<<n, 256, 0, stream>>>(features, (const unsigned*)h1, rowstart, deg,
                                       inv, elist, emb);

    const int MB = (n + 63) / 64;  // 782
    mlp12<<<MB, 256, 0, stream>>>(emb, Wt1, Wt2, b_enc1, b_enc3, encoded, enc16, n);
    mlp34<<<MB, 256, 0, stream>>>(enc16, Wt3, Wt4, b_dec1, b_dec3, decoded, n);
}

// Round 9
// 341.138 us; speedup vs baseline: 1.2173x; 1.0280x over previous
//
#include <hip/hip_runtime.h>
#include <hip/hip_bf16.h>

#define NODELEN 394
#define IN_DIM 788
#define H2DIM 192
#define EMBDIM 128
#define NCHUNK 197   // 394 elems = 197 x (float2 | uint-packed-bf16x2)

typedef __attribute__((ext_vector_type(4))) float f32x4;
typedef __attribute__((ext_vector_type(8))) short bfrag;  // 8 bf16 = 4 VGPRs

// raw barrier: LDS-coherent, does NOT drain vmcnt (global prefetches stay in flight)
#define LBAR() do { asm volatile("s_waitcnt lgkmcnt(0)" ::: "memory"); \
                    __builtin_amdgcn_s_barrier(); } while (0)

static __device__ __forceinline__ unsigned short f2bf(float f) {
    union { float f; unsigned u; } v; v.f = f;
    unsigned r = v.u + 0x7FFFu + ((v.u >> 16) & 1u);  // round-to-nearest-even
    return (unsigned short)(r >> 16);
}
static __device__ __forceinline__ float bf2f(unsigned short h) {
    union { unsigned u; float f; } v; v.u = ((unsigned)h) << 16;
    return v.f;
}
static __device__ __forceinline__ unsigned short f2bf_fast(float f) {
    __hip_bfloat16 h = __float2bfloat16(f);
    union { __hip_bfloat16 h; unsigned short u; } c; c.h = h; return c.u;
}

// ---------------- CSR build ----------------

__global__ void count_deg(const int* __restrict__ dst, int* __restrict__ deg, int e) {
    int i = blockIdx.x * blockDim.x + threadIdx.x;
    if (i < e) atomicAdd(&deg[dst[i]], 1);
}

__global__ void block_sum(const int* __restrict__ deg, int* __restrict__ bsum, int n) {
    __shared__ int s[256];
    int t = threadIdx.x;
    int i = blockIdx.x * 256 + t;
    s[t] = (i < n) ? deg[i] : 0;
    __syncthreads();
    for (int d = 128; d > 0; d >>= 1) {
        if (t < d) s[t] += s[t + d];
        __syncthreads();
    }
    if (t == 0) bsum[blockIdx.x] = s[0];
}

__global__ void scan_bsums(int* bsum, int nb) {
    __shared__ int s[256];
    int t = threadIdx.x;
    int x0 = (t < nb) ? bsum[t] : 0;
    s[t] = x0;
    __syncthreads();
    for (int d = 1; d < 256; d <<= 1) {
        int u = (t >= d) ? s[t - d] : 0;
        __syncthreads();
        s[t] += u;
        __syncthreads();
    }
    if (t < nb) bsum[t] = s[t] - x0;
}

__global__ void block_scan(const int* __restrict__ deg, const int* __restrict__ boff,
                           int* __restrict__ rowstart, int* __restrict__ cursor,
                           float* __restrict__ inv, int n) {
    __shared__ int s[256];
    int t = threadIdx.x;
    int i = blockIdx.x * 256 + t;
    int x0 = (i < n) ? deg[i] : 0;
    s[t] = x0;
    __syncthreads();
    for (int d = 1; d < 256; d <<= 1) {
        int u = (t >= d) ? s[t - d] : 0;
        __syncthreads();
        s[t] += u;
        __syncthreads();
    }
    if (i < n) {
        int r = boff[blockIdx.x] + s[t] - x0;
        rowstart[i] = r;
        cursor[i] = r;
        inv[i] = 1.0f / fmaxf((float)x0, 1.0f);
    }
}

__global__ void fill_edges(const int* __restrict__ src, const int* __restrict__ dst,
                           int* __restrict__ cursor, int* __restrict__ elist, int e) {
    int i = blockIdx.x * blockDim.x + threadIdx.x;
    if (i < e) {
        int p = atomicAdd(&cursor[dst[i]], 1);
        elist[p] = src[i];
    }
}

// ---------------- aggregation (gather) ----------------

__global__ __launch_bounds__(256) void gather1(
        const float* __restrict__ feat, const int* __restrict__ rowstart,
        const int* __restrict__ deg, const float* __restrict__ inv,
        const int* __restrict__ elist, unsigned short* __restrict__ h1) {
    const int node = blockIdx.x;
    const int c = threadIdx.x;
    if (c >= NCHUNK) return;
    const int beg = rowstart[node];
    const int dc = deg[node];
    const float s = inv[node];
    const size_t off = (size_t)c * 2;

    float ax = 0.f, ay = 0.f, bx = 0.f, by = 0.f;
    float cx = 0.f, cy = 0.f, dx = 0.f, dy = 0.f;
    int j = 0;
    for (; j + 3 < dc; j += 4) {
        int n0 = elist[beg + j], n1 = elist[beg + j + 1];
        int n2 = elist[beg + j + 2], n3 = elist[beg + j + 3];
        float2 v0 = *(const float2*)(feat + (size_t)n0 * NODELEN + off);
        float2 v1 = *(const float2*)(feat + (size_t)n1 * NODELEN + off);
        float2 v2 = *(const float2*)(feat + (size_t)n2 * NODELEN + off);
        float2 v3 = *(const float2*)(feat + (size_t)n3 * NODELEN + off);
        ax += v0.x; ay += v0.y; bx += v1.x; by += v1.y;
        cx += v2.x; cy += v2.y; dx += v3.x; dy += v3.y;
    }
    for (; j < dc; ++j) {
        int n0 = elist[beg + j];
        float2 v0 = *(const float2*)(feat + (size_t)n0 * NODELEN + off);
        ax += v0.x; ay += v0.y;
    }
    float fx = (ax + bx + cx + dx) * s;
    float fy = (ay + by + cy + dy) * s;
    if (c == 0) fx = 0.f;
    unsigned out = ((unsigned)f2bf(fy) << 16) | (unsigned)f2bf(fx);
    *(unsigned*)(h1 + (size_t)node * NODELEN + off) = out;
}

// emb fp32 [n][788]; optionally emb16 bf16 [n][800] (cols 788..799 zero)
__global__ __launch_bounds__(256) void gather2_emb(
        const float* __restrict__ feat, const unsigned* __restrict__ h1,
        const int* __restrict__ rowstart, const int* __restrict__ deg,
        const float* __restrict__ inv, const int* __restrict__ elist,
        float* __restrict__ emb, unsigned* __restrict__ emb16u) {
    const int node = blockIdx.x;
    const int c = threadIdx.x;
    if (c >= NCHUNK) return;
    const int beg = rowstart[node];
    const int dc = deg[node];
    const float s = inv[node];

    float ax = 0.f, ay = 0.f, bx = 0.f, by = 0.f;
    float cx = 0.f, cy = 0.f, dx = 0.f, dy = 0.f;
    int j = 0;
    for (; j + 3 < dc; j += 4) {
        int n0 = elist[beg + j], n1 = elist[beg + j + 1];
        int n2 = elist[beg + j + 2], n3 = elist[beg + j + 3];
        unsigned u0 = h1[(size_t)n0 * NCHUNK + c];
        unsigned u1 = h1[(size_t)n1 * NCHUNK + c];
        unsigned u2 = h1[(size_t)n2 * NCHUNK + c];
        unsigned u3 = h1[(size_t)n3 * NCHUNK + c];
        ax += bf2f((unsigned short)u0); ay += bf2f((unsigned short)(u0 >> 16));
        bx += bf2f((unsigned short)u1); by += bf2f((unsigned short)(u1 >> 16));
        cx += bf2f((unsigned short)u2); cy += bf2f((unsigned short)(u2 >> 16));
        dx += bf2f((unsigned short)u3); dy += bf2f((unsigned short)(u3 >> 16));
    }
    for (; j < dc; ++j) {
        int n0 = elist[beg + j];
        unsigned u0 = h1[(size_t)n0 * NCHUNK + c];
        ax += bf2f((unsigned short)u0); ay += bf2f((unsigned short)(u0 >> 16));
    }
    float hx = (ax + bx + cx + dx) * s;
    float hy = (ay + by + cy + dy) * s;

    const float* fr = feat + (size_t)node * NODELEN;
    float* er = emb + (size_t)node * IN_DIM;
    float2 fv = *(const float2*)(fr + c * 2);
    if (c == 0) { fv.x = 0.f; hx = 0.f; }
    *(float2*)(er + c * 2) = fv;
    float2 hv; hv.x = hx; hv.y = hy;
    *(float2*)(er + NODELEN + c * 2) = hv;

    if (emb16u) {
        unsigned* e16 = emb16u + (size_t)node * 400;
        e16[c]          = ((unsigned)f2bf(fv.y) << 16) | (unsigned)f2bf(fv.x);
        e16[NCHUNK + c] = ((unsigned)f2bf(hy)  << 16) | (unsigned)f2bf(hx);
        if (c < 6) e16[394 + c] = 0u;
    }
}

// ---------------- fused weight pre-transpose ----------
__device__ __forceinline__ void tr_one(const float* W, unsigned short* Wt,
                                       int K, int N, int Kp, int idx) {
    int nrow = idx / Kp, k = idx - nrow * Kp;
    Wt[idx] = (k < K) ? f2bf(W[(size_t)k * N + nrow]) : (unsigned short)0;
}

#define T1E (192 * 800)
#define T2E (128 * 192)
#define T3E (192 * 128)
#define T4E (788 * 192)

__global__ void transpose_all(const float* __restrict__ W1, unsigned short* __restrict__ Wt1,
                              const float* __restrict__ W2, unsigned short* __restrict__ Wt2,
                              const float* __restrict__ W3, unsigned short* __restrict__ Wt3,
                              const float* __restrict__ W4, unsigned short* __restrict__ Wt4) {
    int idx = blockIdx.x * 256 + threadIdx.x;
    if (idx < T1E) { tr_one(W1, Wt1, IN_DIM, H2DIM, 800, idx); return; }
    idx -= T1E;
    if (idx < T2E) { tr_one(W2, Wt2, H2DIM, EMBDIM, 192, idx); return; }
    idx -= T2E;
    if (idx < T3E) { tr_one(W3, Wt3, EMBDIM, H2DIM, 128, idx); return; }
    idx -= T3E;
    if (idx < T4E) { tr_one(W4, Wt4, H2DIM, IN_DIM, 192, idx); return; }
}

// ---------------- MLP kernels: BM=128 (391 blocks, single scheduling wave) -------
// Swizzled LDS addressing (in shorts): per-row bijection on 16B slots.
static __device__ __forceinline__ int bs_addr(int r, int s) {           // Bs[192][32]
    return r * 32 + ((s ^ ((r >> 1) & 3)) << 3);
}
static __device__ __forceinline__ int xy_base(int r, int s) {           // XY[128][192]
    int ph = (s & 24) | ((s ^ r) & 7);
    return r * 192 + (ph << 3);
}
static __device__ __forceinline__ int xy_addr_s(int r, int col) { return xy_base(r, col >> 3) + (col & 7); }

static __device__ __forceinline__ bfrag load_af_bf(const unsigned short* A800, int gm, int M, int col) {
    const bfrag zf = {0, 0, 0, 0, 0, 0, 0, 0};
    return (gm < M) ? *(const bfrag*)(A800 + (size_t)gm * 800 + col) : zf;
}
static __device__ __forceinline__ bfrag load_af_f32(const float* A, int gm, int M, int col) {
    float t[8];
    #pragma unroll
    for (int q = 0; q < 8; ++q) t[q] = 0.f;
    if (gm < M) {
        const float* rp = A + (size_t)gm * IN_DIM;
        if (col + 8 <= IN_DIM) {
            float4 v0 = *(const float4*)(rp + col), v1 = *(const float4*)(rp + col + 4);
            t[0] = v0.x; t[1] = v0.y; t[2] = v0.z; t[3] = v0.w;
            t[4] = v1.x; t[5] = v1.y; t[6] = v1.z; t[7] = v1.w;
        } else {
            #pragma unroll
            for (int q = 0; q < 8; ++q) if (col + q < IN_DIM) t[q] = rp[col + q];
        }
    }
    union { unsigned short u[8]; bfrag v; } pk;
    #pragma unroll
    for (int q = 0; q < 8; ++q) pk.u[q] = f2bf_fast(t[q]);
    return pk.v;
}

// ===== kernel A: stage1+2  emb -> x(lds) -> encoded(f32) + enc16(bf16) ==========
template <int ABF>
__global__ __launch_bounds__(256, 2) void mlp12(
    const void* __restrict__ Aemb,           // ABF ? bf16[n][800] : f32[n][788]
    const unsigned short* __restrict__ Wt1,  // [192][800]
    const unsigned short* __restrict__ Wt2,  // [128][192]
    const float* __restrict__ b1, const float* __restrict__ b2,
    float* __restrict__ encoded, unsigned short* __restrict__ enc16, int M)
{
    __shared__ unsigned short XY[128 * 192];     // 48 KB
    __shared__ unsigned short Bs[2][192 * 32];   // 24 KB

    const int tid = threadIdx.x;
    const int wid = tid >> 6, l = tid & 63;
    const int wm = wid >> 1, wn = wid & 1;       // 2x2 waves; wave tile 64 x 96
    const int lr = l & 15, lk = l >> 4;
    const int m0 = blockIdx.x * 128;

    const int r0 = tid >> 2, s0 = tid & 3;       // staging units
    const int r1 = r0 + 64, r2 = r0 + 128;
    const int bw0 = bs_addr(r0, s0);
    const int bw1 = bs_addr(r1, s0);
    const int bw2 = bs_addr(r2, s0);
    int brd6[6], brd4[4];
    #pragma unroll
    for (int j = 0; j < 6; ++j) brd6[j] = bs_addr(wn * 96 + j * 16 + lr, lk);
    #pragma unroll
    for (int j = 0; j < 4; ++j) brd4[j] = bs_addr(wn * 64 + j * 16 + lr, lk);

    int gmA[4];
    #pragma unroll
    for (int i = 0; i < 4; ++i) gmA[i] = m0 + wm * 64 + i * 16 + lr;

    // ---- STAGE 1: K=800 (25 steps), N=192, dbuf B + raw barriers ----
    {
        f32x4 acc[4][6];
        #pragma unroll
        for (int i = 0; i < 4; ++i)
            #pragma unroll
            for (int j = 0; j < 6; ++j) acc[i][j] = (f32x4){0.f, 0.f, 0.f, 0.f};

        bfrag afC[4], afN[4], bN[3];
        #pragma unroll
        for (int i = 0; i < 4; ++i)
            afC[i] = ABF ? load_af_bf((const unsigned short*)Aemb, gmA[i], M, lk * 8)
                         : load_af_f32((const float*)Aemb, gmA[i], M, lk * 8);
        // prologue: stage B(kt=0) into Bs[0]
        *(bfrag*)&Bs[0][bw0] = *(const bfrag*)(Wt1 + (size_t)r0 * 800 + s0 * 8);
        *(bfrag*)&Bs[0][bw1] = *(const bfrag*)(Wt1 + (size_t)r1 * 800 + s0 * 8);
        *(bfrag*)&Bs[0][bw2] = *(const bfrag*)(Wt1 + (size_t)r2 * 800 + s0 * 8);
        LBAR();

        #pragma unroll 5
        for (int kt = 0; kt < 25; ++kt) {
            if (kt < 24) {
                int k0 = (kt + 1) * 32;
                #pragma unroll
                for (int i = 0; i < 4; ++i)
                    afN[i] = ABF ? load_af_bf((const unsigned short*)Aemb, gmA[i], M, k0 + lk * 8)
                                 : load_af_f32((const float*)Aemb, gmA[i], M, k0 + lk * 8);
                bN[0] = *(const bfrag*)(Wt1 + (size_t)r0 * 800 + k0 + s0 * 8);
                bN[1] = *(const bfrag*)(Wt1 + (size_t)r1 * 800 + k0 + s0 * 8);
                bN[2] = *(const bfrag*)(Wt1 + (size_t)r2 * 800 + k0 + s0 * 8);
            }
            const unsigned short* B = Bs[kt & 1];
            bfrag bf[6];
            #pragma unroll
            for (int j = 0; j < 6; ++j) bf[j] = *(const bfrag*)&B[brd6[j]];
            #pragma unroll
            for (int i = 0; i < 4; ++i)
                #pragma unroll
                for (int j = 0; j < 6; ++j)
                    acc[i][j] = __builtin_amdgcn_mfma_f32_16x16x32_bf16(afC[i], bf[j], acc[i][j], 0, 0, 0);
            if (kt < 24) {
                unsigned short* Bn = Bs[(kt + 1) & 1];
                *(bfrag*)&Bn[bw0] = bN[0];
                *(bfrag*)&Bn[bw1] = bN[1];
                *(bfrag*)&Bn[bw2] = bN[2];
                LBAR();
                #pragma unroll
                for (int i = 0; i < 4; ++i) afC[i] = afN[i];
            }
        }
        float bv[6];
        #pragma unroll
        for (int j = 0; j < 6; ++j) bv[j] = b1[wn * 96 + j * 16 + lr];
        #pragma unroll
        for (int i = 0; i < 4; ++i)
            #pragma unroll
            for (int j = 0; j < 6; ++j)
                #pragma unroll
                for (int r = 0; r < 4; ++r) {
                    int m = wm * 64 + i * 16 + lk * 4 + r;
                    int n1 = wn * 96 + j * 16 + lr;
                    XY[xy_addr_s(m, n1)] = f2bf_fast(fmaxf(acc[i][j][r] + bv[j], 0.f));
                }
    }
    __syncthreads();   // x visible, stage-1 Bs reads done

    // ---- STAGE 2: K=192 (6 steps), N=128, dbuf B ----
    {
        f32x4 acc[4][4];
        #pragma unroll
        for (int i = 0; i < 4; ++i)
            #pragma unroll
            for (int j = 0; j < 4; ++j) acc[i][j] = (f32x4){0.f, 0.f, 0.f, 0.f};

        bfrag bN[2];
        *(bfrag*)&Bs[0][bw0] = *(const bfrag*)(Wt2 + (size_t)r0 * 192 + s0 * 8);
        *(bfrag*)&Bs[0][bw1] = *(const bfrag*)(Wt2 + (size_t)r1 * 192 + s0 * 8);
        LBAR();

        #pragma unroll
        for (int kt = 0; kt < 6; ++kt) {
            if (kt < 5) {
                int k0 = (kt + 1) * 32;
                bN[0] = *(const bfrag*)(Wt2 + (size_t)r0 * 192 + k0 + s0 * 8);
                bN[1] = *(const bfrag*)(Wt2 + (size_t)r1 * 192 + k0 + s0 * 8);
            }
            const unsigned short* B = Bs[kt & 1];
            bfrag af[4], bf[4];
            #pragma unroll
            for (int i = 0; i < 4; ++i)
                af[i] = *(const bfrag*)&XY[xy_base(wm * 64 + i * 16 + lr, kt * 4 + lk)];
            #pragma unroll
            for (int j = 0; j < 4; ++j) bf[j] = *(const bfrag*)&B[brd4[j]];
            #pragma unroll
            for (int i = 0; i < 4; ++i)
                #pragma unroll
                for (int j = 0; j < 4; ++j)
                    acc[i][j] = __builtin_amdgcn_mfma_f32_16x16x32_bf16(af[i], bf[j], acc[i][j], 0, 0, 0);
            if (kt < 5) {
                unsigned short* Bn = Bs[(kt + 1) & 1];
                *(bfrag*)&Bn[bw0] = bN[0];
                *(bfrag*)&Bn[bw1] = bN[1];
                LBAR();
            }
        }

        float bv[4];
        #pragma unroll
        for (int j = 0; j < 4; ++j) bv[j] = b2[wn * 64 + j * 16 + lr];
        #pragma unroll
        for (int i = 0; i < 4; ++i)
            #pragma unroll
            for (int j = 0; j < 4; ++j)
                #pragma unroll
                for (int r = 0; r < 4; ++r) {
                    int m = wm * 64 + i * 16 + lk * 4 + r;
                    int nn = wn * 64 + j * 16 + lr;
                    float v = acc[i][j][r] + bv[j];
                    int gm = m0 + m;
                    if (gm < M) {
                        encoded[(size_t)gm * EMBDIM + nn] = v;
                        enc16[(size_t)gm * EMBDIM + nn] = f2bf_fast(v);
                    }
                }
    }
}

// ===== kernel B: stage3+4  enc16 -> y(lds) -> decoded(f32) ======================
__global__ __launch_bounds__(256, 2) void mlp34(
    const unsigned short* __restrict__ enc16,
    const unsigned short* __restrict__ Wt3,  // [192][128]
    const unsigned short* __restrict__ Wt4,  // [788][192]
    const float* __restrict__ b3, const float* __restrict__ b4,
    float* __restrict__ decoded, int M)
{
    __shared__ unsigned short XY[128 * 192];     // 48 KB (y)
    __shared__ unsigned short Bs[2][192 * 32];   // 24 KB

    const int tid = threadIdx.x;
    const int wid = tid >> 6, l = tid & 63;
    const int wm = wid >> 1, wn = wid & 1;
    const int lr = l & 15, lk = l >> 4;
    const int m0 = blockIdx.x * 128;
    const bfrag zf = {0, 0, 0, 0, 0, 0, 0, 0};

    const int r0 = tid >> 2, s0 = tid & 3;
    const int r1 = r0 + 64, r2 = r0 + 128;
    const int bw0 = bs_addr(r0, s0);
    const int bw1 = bs_addr(r1, s0);
    const int bw2 = bs_addr(r2, s0);
    int brd6[6], brd4[4];
    #pragma unroll
    for (int j = 0; j < 6; ++j) brd6[j] = bs_addr(wn * 96 + j * 16 + lr, lk);
    #pragma unroll
    for (int j = 0; j < 4; ++j) brd4[j] = bs_addr(wn * 64 + j * 16 + lr, lk);

    int gmA[4];
    #pragma unroll
    for (int i = 0; i < 4; ++i) gmA[i] = m0 + wm * 64 + i * 16 + lr;

    // ---- STAGE 3: y = relu(enc @ W3 + b3), K=128 (4 steps), N=192 ----
    {
        f32x4 acc[4][6];
        #pragma unroll
        for (int i = 0; i < 4; ++i)
            #pragma unroll
            for (int j = 0; j < 6; ++j) acc[i][j] = (f32x4){0.f, 0.f, 0.f, 0.f};

        bfrag afC[4], afN[4], bN[3];
        #pragma unroll
        for (int i = 0; i < 4; ++i)
            afC[i] = (gmA[i] < M) ? *(const bfrag*)(enc16 + (size_t)gmA[i] * EMBDIM + lk * 8) : zf;
        *(bfrag*)&Bs[0][bw0] = *(const bfrag*)(Wt3 + (size_t)r0 * 128 + s0 * 8);
        *(bfrag*)&Bs[0][bw1] = *(const bfrag*)(Wt3 + (size_t)r1 * 128 + s0 * 8);
        *(bfrag*)&Bs[0][bw2] = *(const bfrag*)(Wt3 + (size_t)r2 * 128 + s0 * 8);
        LBAR();

        #pragma unroll
        for (int kt = 0; kt < 4; ++kt) {
            if (kt < 3) {
                int k0 = (kt + 1) * 32;
                #pragma unroll
                for (int i = 0; i < 4; ++i)
                    afN[i] = (gmA[i] < M)
                        ? *(const bfrag*)(enc16 + (size_t)gmA[i] * EMBDIM + k0 + lk * 8) : zf;
                bN[0] = *(const bfrag*)(Wt3 + (size_t)r0 * 128 + k0 + s0 * 8);
                bN[1] = *(const bfrag*)(Wt3 + (size_t)r1 * 128 + k0 + s0 * 8);
                bN[2] = *(const bfrag*)(Wt3 + (size_t)r2 * 128 + k0 + s0 * 8);
            }
            const unsigned short* B = Bs[kt & 1];
            bfrag bf[6];
            #pragma unroll
            for (int j = 0; j < 6; ++j) bf[j] = *(const bfrag*)&B[brd6[j]];
            #pragma unroll
            for (int i = 0; i < 4; ++i)
                #pragma unroll
                for (int j = 0; j < 6; ++j)
                    acc[i][j] = __builtin_amdgcn_mfma_f32_16x16x32_bf16(afC[i], bf[j], acc[i][j], 0, 0, 0);
            if (kt < 3) {
                unsigned short* Bn = Bs[(kt + 1) & 1];
                *(bfrag*)&Bn[bw0] = bN[0];
                *(bfrag*)&Bn[bw1] = bN[1];
                *(bfrag*)&Bn[bw2] = bN[2];
                LBAR();
                #pragma unroll
                for (int i = 0; i < 4; ++i) afC[i] = afN[i];
            }
        }

        float bv[6];
        #pragma unroll
        for (int j = 0; j < 6; ++j) bv[j] = b3[wn * 96 + j * 16 + lr];
        #pragma unroll
        for (int i = 0; i < 4; ++i)
            #pragma unroll
            for (int j = 0; j < 6; ++j)
                #pragma unroll
                for (int r = 0; r < 4; ++r) {
                    int m = wm * 64 + i * 16 + lk * 4 + r;
                    int nc = wn * 96 + j * 16 + lr;
                    XY[xy_addr_s(m, nc)] = f2bf_fast(fmaxf(acc[i][j][r] + bv[j], 0.f));
                }
    }
    __syncthreads();   // y visible

    // ---- STAGE 4: dec = y @ W4 + b4, K=192 (6 steps), N=788 (7 x 128) ----
    {
        bfrag af4[6][4];   // hoisted once, reused across chunks
        #pragma unroll
        for (int q = 0; q < 6; ++q)
            #pragma unroll
            for (int i = 0; i < 4; ++i)
                af4[q][i] = *(const bfrag*)&XY[xy_base(wm * 64 + i * 16 + lr, q * 4 + lk)];

        bfrag bN[2];
        // prologue: chunk 0, kt 0 (rows r0,r1 < 128 < 788)
        *(bfrag*)&Bs[0][bw0] = *(const bfrag*)(Wt4 + (size_t)r0 * 192 + s0 * 8);
        *(bfrag*)&Bs[0][bw1] = *(const bfrag*)(Wt4 + (size_t)r1 * 192 + s0 * 8);
        LBAR();

        for (int nc = 0; nc < 7; ++nc) {
            f32x4 acc[4][4];
            #pragma unroll
            for (int i = 0; i < 4; ++i)
                #pragma unroll
                for (int j = 0; j < 4; ++j) acc[i][j] = (f32x4){0.f, 0.f, 0.f, 0.f};

            #pragma unroll
            for (int kt = 0; kt < 6; ++kt) {
                const bool last = (nc == 6) && (kt == 5);
                if (!last) {
                    int nn = (kt < 5) ? nc : nc + 1;
                    int nk = (kt < 5) ? (kt + 1) * 32 : 0;
                    int g0 = nn * 128 + r0, g1 = nn * 128 + r1;
                    bN[0] = (g0 < IN_DIM) ? *(const bfrag*)(Wt4 + (size_t)g0 * 192 + nk + s0 * 8) : zf;
                    bN[1] = (g1 < IN_DIM) ? *(const bfrag*)(Wt4 + (size_t)g1 * 192 + nk + s0 * 8) : zf;
                }
                const unsigned short* B = Bs[kt & 1];
                bfrag bf[4];
                #pragma unroll
                for (int j = 0; j < 4; ++j) bf[j] = *(const bfrag*)&B[brd4[j]];
                #pragma unroll
                for (int i = 0; i < 4; ++i)
                    #pragma unroll
                    for (int j = 0; j < 4; ++j)
                        acc[i][j] = __builtin_amdgcn_mfma_f32_16x16x32_bf16(af4[kt][i], bf[j], acc[i][j], 0, 0, 0);
                if (!last) {
                    unsigned short* Bn = Bs[(kt + 1) & 1];
                    *(bfrag*)&Bn[bw0] = bN[0];
                    *(bfrag*)&Bn[bw1] = bN[1];
                    LBAR();
                }
            }

            float bv[4];
            #pragma unroll
            for (int j = 0; j < 4; ++j) {
                int nn = nc * 128 + wn * 64 + j * 16 + lr;
                bv[j] = (nn < IN_DIM) ? b4[nn] : 0.f;
            }
            #pragma unroll
            for (int i = 0; i < 4; ++i)
                #pragma unroll
                for (int j = 0; j < 4; ++j)
                    #pragma unroll
                    for (int r = 0; r < 4; ++r) {
                        int gm = m0 + wm * 64 + i * 16 + lk * 4 + r;
                        int nn = nc * 128 + wn * 64 + j * 16 + lr;
                        if (gm < M && nn < IN_DIM)
                            decoded[(size_t)gm * IN_DIM + nn] = acc[i][j][r] + bv[j];
                    }
        }
    }
}

// ---------------- launch ----------------

extern "C" void kernel_launch(void* const* d_in, const int* in_sizes, int n_in,
                              void* d_out, int out_size, void* d_ws, size_t ws_size,
                              hipStream_t stream) {
    const float* features = (const float*)d_in[0];
    const int*   src      = (const int*)d_in[1];
    const int*   dst      = (const int*)d_in[2];
    const float* W_enc1   = (const float*)d_in[3];
    const float* b_enc1   = (const float*)d_in[4];
    const float* W_enc3   = (const float*)d_in[5];
    const float* b_enc3   = (const float*)d_in[6];
    const float* W_dec1   = (const float*)d_in[7];
    const float* b_dec1   = (const float*)d_in[8];
    const float* W_dec3   = (const float*)d_in[9];
    const float* b_dec3   = (const float*)d_in[10];

    const int n = in_sizes[0] / NODELEN;  // 50000
    const int e = in_sizes[1];            // 200000

    // d_out layout: encoded [n,128] | decoded [n,788] | emb [n,788]
    float* encoded = (float*)d_out;
    float* decoded = encoded + (size_t)n * EMBDIM;
    float* emb     = decoded + (size_t)n * IN_DIM;

    // ws layout (bytes)
    char* ws = (char*)d_ws;
    unsigned short* h1    = (unsigned short*)(ws + 0);        // n*394*2 (reused by enc16)
    unsigned short* enc16 = (unsigned short*)(ws + 0);        // n*128*2 (after gathers)
    unsigned short* Wt1 = (unsigned short*)(ws + 40000000);
    unsigned short* Wt2 = (unsigned short*)(ws + 40400000);
    unsigned short* Wt3 = (unsigned short*)(ws + 40500000);
    unsigned short* Wt4 = (unsigned short*)(ws + 40600000);
    float* inv          = (float*)(ws + 41000000);
    int*   deg          = (int*)  (ws + 41200000);
    int*   rowstart     = (int*)  (ws + 41400000);
    int*   cursor       = (int*)  (ws + 41600000);
    int*   elist        = (int*)  (ws + 41800000);
    int*   bsum         = (int*)  (ws + 42600000);
    unsigned short* emb16 = (unsigned short*)(ws + 44000000); // n*800*2 = 80 MB
    const size_t NEED = 44000000ull + (size_t)n * 800 * 2;    // 124 MB
    const int useBF = (ws_size >= NEED) ? 1 : 0;

    const int nb = (n + 255) / 256;
    const int eb = (e + 255) / 256;

    transpose_all<<<(T1E + T2E + T3E + T4E + 255) / 256, 256, 0, stream>>>(
        W_enc1, Wt1, W_enc3, Wt2, W_dec1, Wt3, W_dec3, Wt4);

    hipMemsetAsync(deg, 0, (size_t)n * sizeof(int), stream);
    count_deg<<<eb, 256, 0, stream>>>(dst, deg, e);
    block_sum<<<nb, 256, 0, stream>>>(deg, bsum, n);
    scan_bsums<<<1, 256, 0, stream>>>(bsum, nb);
    block_scan<<<nb, 256, 0, stream>>>(deg, bsum, rowstart, cursor, inv, n);
    fill_edges<<<eb, 256, 0, stream>>>(src, dst, cursor, elist, e);

    gather1<<<n, 256, 0, stream>>>(features, rowstart, deg, inv, elist, h1);
    gather2_emb<<<n, 256, 0, stream>>>(features, (const unsigned*)h1, rowstart, deg,
                                       inv, elist, emb,
                                       useBF ? (unsigned*)emb16 : nullptr);

    const int MB = (n + 127) / 128;  // 391 blocks: single scheduling wave at 2/CU
    if (useBF) {
        mlp12<1><<<MB, 256, 0, stream>>>(emb16, Wt1, Wt2, b_enc1, b_enc3, encoded, enc16, n);
    } else {
        mlp12<0><<<MB, 256, 0, stream>>>(emb, Wt1, Wt2, b_enc1, b_enc3, encoded, enc16, n);
    }
    mlp34<<<MB, 256, 0, stream>>>(enc16, Wt3, Wt4, b_dec1, b_dec3, decoded, n);
}